// Round 7
// baseline (188.924 us; speedup 1.0000x reference)
//
#include <hip/hip_runtime.h>

// Shapes: genes[32][2048][4], smiles[32][2048][1024], w_ngf[4], w_genes[2048][512],
//         b_genes[512], w_smiles[1024][512], b_smiles[512], v[512] -> out[32][1024]
//
// Fused design: scores are bounded (|score| <= ||v||_1 ~ 41) so softmax needs no
// max-subtraction -> e^score and the alpha-weighted smiles sum are computed in the
// SAME pass as the GEMM, from the LDS-resident A tile. smiles is read ONCE.

typedef __bf16 bf16_t;
typedef bf16_t bf16x8 __attribute__((ext_vector_type(8)));
typedef float f32x16 __attribute__((ext_vector_type(16)));

__device__ __forceinline__ unsigned short f32_to_bf16_rne(float f) {
    unsigned int u = __builtin_bit_cast(unsigned int, f);
    u = (u + 0x7FFFu + ((u >> 16) & 1u)) >> 16;
    return (unsigned short)u;
}

__device__ __forceinline__ float bf16bits_to_f32(unsigned short u) {
    unsigned int w = ((unsigned int)u) << 16;
    return __builtin_bit_cast(float, w);
}

__device__ __forceinline__ float fast_tanh(float x) {
    float cx = fminf(fmaxf(x, -30.f), 30.f);
    float e = __expf(2.f * cx);
    return (e - 1.f) / (e + 1.f);
}

// K0b: pack w_smiles [1024][512] f32 into 32-col FRAGMENT-MAJOR bf16 for
// mfma_32x32x16. Frag f = atile2*64 + gks16.
// Bp[f][lane][e] = w[gks16*16+(lane>>5)*8+e][atile2*32+(lane&31)]   (HW-validated R6)
__global__ void k0b_pack(const float* __restrict__ w, unsigned short* __restrict__ Bp) {
    int bid  = blockIdx.x;        // 1024 = 16 atile2 * 64 gks16
    int lane = threadIdx.x;       // 64
    int atile2 = bid >> 6, gks16 = bid & 63;
    int col = atile2 * 32 + (lane & 31);
    int k0  = gks16 * 16 + (lane >> 5) * 8;
    unsigned short us[8];
#pragma unroll
    for (int e = 0; e < 8; ++e)
        us[e] = f32_to_bf16_rne(w[(size_t)(k0 + e) * 512 + col]);
    *(uint4*)(Bp + (size_t)bid * 512 + lane * 8) = *(const uint4*)us;
}

// K1a: gc[b][g] = dot(genes[b][g][0..3], w_ngf)
__global__ void k1a_gc(const float4* __restrict__ genes, const float* __restrict__ wngf,
                       float* __restrict__ gc) {
    int i = blockIdx.x * 256 + threadIdx.x;   // 65536 = 32*2048
    float4 g = genes[i];
    gc[i] = g.x * wngf[0] + g.y * wngf[1] + g.z * wngf[2] + g.w * wngf[3];
}

// K1b: x[b][a] += sum_{g in chunk} gc[b][g] * w_genes[g][a]   (x pre-zeroed)
__global__ void k1b_x(const float* __restrict__ gc, const float* __restrict__ wg,
                      float* __restrict__ x) {
    __shared__ float gcl[256];
    int bx = blockIdx.x;              // 512 = 32 b * 2 a-halves * 8 g-chunks
    int b = bx >> 4, ah = (bx >> 3) & 1, gch = bx & 7;
    int g0 = gch * 256;
    gcl[threadIdx.x] = gc[b * 2048 + g0 + threadIdx.x];
    __syncthreads();
    int a = ah * 256 + threadIdx.x;
    float s = 0.f;
#pragma unroll 8
    for (int g = 0; g < 256; ++g) s += gcl[g] * wg[(size_t)(g0 + g) * 512 + a];
    atomicAdd(&x[b * 512 + a], s);
}

// K2 mega: GEMM + tanh + dot(v) + exp + weighted smiles sum, one pass.
// Block: 1024 thr (16 waves), 64 rows, A[64][1024] bf16 resident in 128KB LDS.
// Wave w: 64 rows x cols [w*32, w*32+32) as 2x1 of 32x32x16 MFMA.
// Per K-tile (BK=128): stage slice kt+1 (reg->cvt->LDS, buried mid-compute),
// compute slice kt, one barrier. Epilogue: scores -> e^s -> sum_r e^{s_r}*A[r][h]
// from LDS; per-block partial slots (no global atomics).
__global__ __launch_bounds__(1024, 4) void k2_mega(
    const float* __restrict__ smiles,
    const unsigned short* __restrict__ Bp,
    const float* __restrict__ xraw,
    const float* __restrict__ b_genes,
    const float* __restrict__ b_smiles,
    const float* __restrict__ v,
    float* __restrict__ Zparts,
    float* __restrict__ Oparts)
{
    __shared__ char A_lds[64 * 2048];            // 128 KB: A[64][1024] bf16, swizzled
    __shared__ float score_lds[64];
    __shared__ float eS_lds[64];

    const int tid  = threadIdx.x;
    const int wave = tid >> 6;                   // 0..15
    const int lane = tid & 63;
    const int l31  = lane & 31;
    const int hi   = lane >> 5;
    const int gm0  = blockIdx.x * 64;            // 1024 blocks
    const int bidx = gm0 >> 11;

    // wave's packed-B: frags wave*64 + kt*8 + ks, each 1KB
    const unsigned short* bpp = Bp + (size_t)wave * 64 * 512 + lane * 8;

    // staging: thread owns 8 consecutive floats of the 64x128 tile slice
    const int srow = tid >> 4;                   // 0..63
    const int sg   = tid & 15;                   // 16B granule within 256B window
    const float* sptr = smiles + (size_t)(gm0 + srow) * 1024 + sg * 8;
    char* wrp = A_lds + srow * 2048;
    const int sswz = (srow & 15) << 4;

    if (tid < 64) score_lds[tid] = 0.f;

    float4 st0, st1;
    f32x16 acc[2];
#pragma unroll
    for (int mt = 0; mt < 2; ++mt)
#pragma unroll
        for (int r = 0; r < 16; ++r)
            acc[mt][r] = 0.f;

#define LOADREGS(kt)                                   \
    {   const float* p = sptr + (kt) * 128;            \
        st0 = *(const float4*)(p);                     \
        st1 = *(const float4*)(p + 4); }

#define CONVWRITE(kt)                                                         \
    {   union { unsigned short us[8]; uint4 u4; } pa;                         \
        pa.us[0] = f32_to_bf16_rne(st0.x); pa.us[1] = f32_to_bf16_rne(st0.y); \
        pa.us[2] = f32_to_bf16_rne(st0.z); pa.us[3] = f32_to_bf16_rne(st0.w); \
        pa.us[4] = f32_to_bf16_rne(st1.x); pa.us[5] = f32_to_bf16_rne(st1.y); \
        pa.us[6] = f32_to_bf16_rne(st1.z); pa.us[7] = f32_to_bf16_rne(st1.w); \
        *(uint4*)(wrp + (((kt) * 256 + sg * 16) ^ sswz)) = pa.u4; }

#define COMPUTE4(kt, ks0)                                                       \
    _Pragma("unroll")                                                           \
    for (int ks = (ks0); ks < (ks0) + 4; ++ks) {                                \
        bf16x8 af[2], bfb;                                                      \
        bfb = *(const bf16x8*)(bpp + (size_t)((kt) * 8 + ks) * 512);            \
        _Pragma("unroll")                                                       \
        for (int mt = 0; mt < 2; ++mt) {                                        \
            int row = mt * 32 + l31;                                            \
            int byteoff = row * 2048 +                                          \
                (((kt) * 256 + ks * 32 + hi * 16) ^ ((row & 15) << 4));         \
            af[mt] = *(const bf16x8*)(A_lds + byteoff);                         \
        }                                                                       \
        __builtin_amdgcn_s_setprio(1);                                          \
        _Pragma("unroll")                                                       \
        for (int mt = 0; mt < 2; ++mt)                                          \
            acc[mt] = __builtin_amdgcn_mfma_f32_32x32x16_bf16(                  \
                af[mt], bfb, acc[mt], 0, 0, 0);                                 \
        __builtin_amdgcn_s_setprio(0);                                          \
    }

    // prologue: stage slice 0
    LOADREGS(0);
    CONVWRITE(0);
    __syncthreads();

#pragma unroll 1
    for (int kt = 0; kt < 8; ++kt) {
        if (kt < 7) LOADREGS(kt + 1);     // HBM loads in flight under compute
        COMPUTE4(kt, 0);
        if (kt < 7) CONVWRITE(kt + 1);    // vmcnt wait buried mid-compute
        COMPUTE4(kt, 4);
        if (kt < 7) __syncthreads();      // RAW for slice kt+1 (no WAR: own slice)
    }

#undef LOADREGS
#undef CONVWRITE
#undef COMPUTE4

    // ---- scores: score[row] = sum_a tanh(y + x + b_g + b_s) * v[a] ----
    {
        int a = wave * 32 + l31;
        float xbv = xraw[bidx * 512 + a] + b_genes[a] + b_smiles[a];
        float vv  = v[a];
        float prs[2][16];
#pragma unroll
        for (int mt = 0; mt < 2; ++mt)
#pragma unroll
            for (int r = 0; r < 16; ++r)
                prs[mt][r] = vv * fast_tanh(acc[mt][r] + xbv);
#pragma unroll
        for (int mt = 0; mt < 2; ++mt)
#pragma unroll
            for (int r = 0; r < 16; ++r) {
                float s = prs[mt][r];
                s += __shfl_xor(s, 1);
                s += __shfl_xor(s, 2);
                s += __shfl_xor(s, 4);
                s += __shfl_xor(s, 8);
                s += __shfl_xor(s, 16);
                prs[mt][r] = s;
            }
        if (l31 == 0) {
#pragma unroll
            for (int mt = 0; mt < 2; ++mt)
#pragma unroll
                for (int r = 0; r < 16; ++r) {
                    int row = (r & 3) + 8 * (r >> 2) + 4 * hi;   // C layout (m74/m101)
                    atomicAdd(&score_lds[mt * 32 + row], prs[mt][r]);
                }
        }
    }
    __syncthreads();

    // ---- e^score (bounded, no max-sub) + block Z partial ----
    if (tid < 64) {
        float e = __expf(score_lds[tid]);
        eS_lds[tid] = e;
        float s = e;
#pragma unroll
        for (int m = 1; m <= 32; m <<= 1) s += __shfl_xor(s, m);
        if (tid == 0) Zparts[blockIdx.x] = s;
    }
    __syncthreads();

    // ---- weighted sum from resident LDS: O[h] = sum_r e^{s_r} * A[r][h] ----
    {
        float accO = 0.f;
#pragma unroll 8
        for (int r = 0; r < 64; ++r) {
            unsigned short u = *(const unsigned short*)(
                A_lds + r * 2048 + ((tid * 2) ^ ((r & 15) << 4)));
            accO += eS_lds[r] * bf16bits_to_f32(u);
        }
        Oparts[(size_t)blockIdx.x * 1024 + tid] = accO;
    }
}

// K5: out[b][h] = sum_c Oparts[b*32+c][h] / sum_c Zparts[b*32+c]
__global__ void k5_norm(const float* __restrict__ Zparts,
                        const float* __restrict__ Oparts,
                        float* __restrict__ out)
{
    int i = blockIdx.x * 256 + threadIdx.x;   // 32768 = 32 b * 1024 h
    int b = i >> 10, h = i & 1023;
    float z = 0.f, o = 0.f;
#pragma unroll 8
    for (int c = 0; c < 32; ++c) {
        z += Zparts[b * 32 + c];
        o += Oparts[(size_t)(b * 32 + c) * 1024 + h];
    }
    out[i] = o / z;
}

extern "C" void kernel_launch(void* const* d_in, const int* in_sizes, int n_in,
                              void* d_out, int out_size, void* d_ws, size_t ws_size,
                              hipStream_t stream) {
    const float* genes    = (const float*)d_in[0];
    const float* smiles   = (const float*)d_in[1];
    const float* w_ngf    = (const float*)d_in[2];
    const float* w_genes  = (const float*)d_in[3];
    const float* b_genes  = (const float*)d_in[4];
    const float* w_smiles = (const float*)d_in[5];
    const float* b_smiles = (const float*)d_in[6];
    const float* v        = (const float*)d_in[7];
    float* out = (float*)d_out;

    char* ws = (char*)d_ws;
    unsigned short* Bp = (unsigned short*)(ws);                  // 1 MB packed B
    float* gc     = (float*)(ws + (1 << 20));                    // 256 KB
    float* x      = (float*)(ws + (1 << 20) + (256 << 10));      // 64 KB
    float* Zparts = (float*)(ws + (1 << 20) + (320 << 10));      // 4 KB (1024 f32)
    float* Oparts = (float*)(ws + (1 << 20) + (384 << 10));      // 4 MB (1024x1024 f32)

    // zero atomic-accumulation target: x only (Zparts/Oparts/out fully written)
    hipMemsetAsync(x, 0, (size_t)64 * 1024, stream);

    k0b_pack<<<1024, 64, 0, stream>>>(w_smiles, Bp);
    k1a_gc<<<256, 256, 0, stream>>>((const float4*)genes, w_ngf, gc);
    k1b_x<<<512, 256, 0, stream>>>(gc, w_genes, x);
    k2_mega<<<1024, 1024, 0, stream>>>(smiles, Bp, x, b_genes, b_smiles, v,
                                       Zparts, Oparts);
    k5_norm<<<128, 256, 0, stream>>>(Zparts, Oparts, out);
}

// Round 8
// 172.271 us; speedup vs baseline: 1.0967x; 1.0967x over previous
//
#include <hip/hip_runtime.h>

// Shapes: genes[32][2048][4], smiles[32][2048][1024], w_ngf[4], w_genes[2048][512],
//         b_genes[512], w_smiles[1024][512], b_smiles[512], v[512] -> out[32][1024]

typedef __bf16 bf16_t;
typedef bf16_t bf16x8 __attribute__((ext_vector_type(8)));
typedef float f32x4 __attribute__((ext_vector_type(4)));

__device__ __forceinline__ unsigned short f32_to_bf16_rne(float f) {
    unsigned int u = __builtin_bit_cast(unsigned int, f);
    u = (u + 0x7FFFu + ((u >> 16) & 1u)) >> 16;
    return (unsigned short)u;
}

__device__ __forceinline__ float fast_tanh(float x) {
    float cx = fminf(fmaxf(x, -30.f), 30.f);
    float e = __expf(2.f * cx);
    return (e - 1.f) / (e + 1.f);
}

// K0b: pack w_smiles [1024][512] f32 into FRAGMENT-MAJOR bf16 (16x16 frags, R3 version).
// Bp[frag=atile*32+gks][lane][e] = w[gks*32 + (lane>>4)*8 + e][atile*16 + (lane&15)]
__global__ void k0b_pack(const float* __restrict__ w, unsigned short* __restrict__ Bp) {
    int bid  = blockIdx.x;        // 1024 = 32 atiles * 32 gks
    int lane = threadIdx.x;       // 64
    int atile = bid >> 5, gks = bid & 31;
    int col = atile * 16 + (lane & 15);
    int k0  = gks * 32 + (lane >> 4) * 8;
    unsigned short us[8];
#pragma unroll
    for (int e = 0; e < 8; ++e)
        us[e] = f32_to_bf16_rne(w[(size_t)(k0 + e) * 512 + col]);
    *(uint4*)(Bp + (size_t)bid * 512 + lane * 8) = *(const uint4*)us;
}

// K1a: gc[b][g] = dot(genes[b][g][0..3], w_ngf)
__global__ void k1a_gc(const float4* __restrict__ genes, const float* __restrict__ wngf,
                       float* __restrict__ gc) {
    int i = blockIdx.x * 256 + threadIdx.x;   // 65536 = 32*2048
    float4 g = genes[i];
    gc[i] = g.x * wngf[0] + g.y * wngf[1] + g.z * wngf[2] + g.w * wngf[3];
}

// K1b: x[b][a] += sum_{g in chunk} gc[b][g] * w_genes[g][a]   (x pre-zeroed)
__global__ void k1b_x(const float* __restrict__ gc, const float* __restrict__ wg,
                      float* __restrict__ x) {
    __shared__ float gcl[256];
    int bx = blockIdx.x;              // 512 = 32 b * 2 a-halves * 8 g-chunks
    int b = bx >> 4, ah = (bx >> 3) & 1, gch = bx & 7;
    int g0 = gch * 256;
    gcl[threadIdx.x] = gc[b * 2048 + g0 + threadIdx.x];
    __syncthreads();
    int a = ah * 256 + threadIdx.x;
    float s = 0.f;
#pragma unroll 8
    for (int g = 0; g < 256; ++g) s += gcl[g] * wg[(size_t)(g0 + g) * 512 + a];
    atomicAdd(&x[b * 512 + a], s);
}

// K2: fused GEMM + tanh + dot(v) -> scores.  (R3 skeleton, 16x16x32 MFMA)
// BK=128 double-buffered LDS (2x16KB). Per K-tile:
//   COMPUTE ks{0,1} -> CONVWRITE A(t+1) (vmcnt wait mid-tile, ds_writes drain
//   under the next MFMAs) -> COMPUTE ks{2,3} -> one __syncthreads.
// Epilogue: per-wave partial scores reduced via LDS atomics, single store.
__global__ __launch_bounds__(512, 4) void k2_scores(
    const float* __restrict__ smiles,
    const unsigned short* __restrict__ Bp,
    const float* __restrict__ xraw,
    const float* __restrict__ b_genes,
    const float* __restrict__ b_smiles,
    const float* __restrict__ v,
    float* __restrict__ scores)
{
    __shared__ unsigned short A_lds[2 * 64 * 128];   // 32 KB, XOR-swizzled 256B rows
    __shared__ float score_lds[64];
    const int tid  = threadIdx.x;
    const int wave = tid >> 6;
    const int lane = tid & 63;
    const int l15  = lane & 15;
    const int l4   = lane >> 4;
    const int gm0  = blockIdx.x * 64;            // 1024 blocks
    const int bidx = gm0 >> 11;
    const int wbase = wave * 64;

    // wave's packed-B base: fragments (wave*4+nt)*32 + gks, each 1KB
    const unsigned short* bpp = Bp + (size_t)(wave * 128) * 512 + lane * 8;

    // staging geometry: thread owns 16 consecutive floats of the 64x128 tile
    const int srow = tid >> 3;                   // 0..63
    const float* sptr = smiles + (size_t)(gm0 + srow) * 1024 + (tid & 7) * 16;
    const int sswz = (srow & 7) << 4;
    char* wr0 = (char*)A_lds + srow * 256 + (((tid & 7) * 32) ^ sswz);
    char* wr1 = (char*)A_lds + srow * 256 + ((((tid & 7) * 32) + 16) ^ sswz);

    if (tid < 64) score_lds[tid] = 0.f;

    float4 st0, st1, st2, st3;

    const f32x4 zero4 = {0.f, 0.f, 0.f, 0.f};
    f32x4 acc[4][4];
#pragma unroll
    for (int mt = 0; mt < 4; ++mt)
#pragma unroll
        for (int nt = 0; nt < 4; ++nt)
            acc[mt][nt] = zero4;

#define LOADREGS(kt)                                   \
    {   const float* p = sptr + (kt) * 128;            \
        st0 = *(const float4*)(p);                     \
        st1 = *(const float4*)(p + 4);                 \
        st2 = *(const float4*)(p + 8);                 \
        st3 = *(const float4*)(p + 12); }

#define CONVWRITE(buf)                                                     \
    {   union { unsigned short us[8]; uint4 u4; } pa, pb;                  \
        pa.us[0] = f32_to_bf16_rne(st0.x); pa.us[1] = f32_to_bf16_rne(st0.y); \
        pa.us[2] = f32_to_bf16_rne(st0.z); pa.us[3] = f32_to_bf16_rne(st0.w); \
        pa.us[4] = f32_to_bf16_rne(st1.x); pa.us[5] = f32_to_bf16_rne(st1.y); \
        pa.us[6] = f32_to_bf16_rne(st1.z); pa.us[7] = f32_to_bf16_rne(st1.w); \
        pb.us[0] = f32_to_bf16_rne(st2.x); pb.us[1] = f32_to_bf16_rne(st2.y); \
        pb.us[2] = f32_to_bf16_rne(st2.z); pb.us[3] = f32_to_bf16_rne(st2.w); \
        pb.us[4] = f32_to_bf16_rne(st3.x); pb.us[5] = f32_to_bf16_rne(st3.y); \
        pb.us[6] = f32_to_bf16_rne(st3.z); pb.us[7] = f32_to_bf16_rne(st3.w); \
        *(uint4*)(wr0 + (buf) * 16384) = pa.u4;                            \
        *(uint4*)(wr1 + (buf) * 16384) = pb.u4; }

#define COMPUTE2(cur, kt, ksb)                                                \
    _Pragma("unroll")                                                         \
    for (int ks4 = (ksb); ks4 < (ksb) + 2; ++ks4) {                           \
        int gks = (kt) * 4 + ks4;                                             \
        bf16x8 af[4], bfb[4];                                                 \
        _Pragma("unroll")                                                     \
        for (int nt = 0; nt < 4; ++nt)                                        \
            bfb[nt] = *(const bf16x8*)(bpp + (nt * 32 + gks) * 512);          \
        _Pragma("unroll")                                                     \
        for (int mt = 0; mt < 4; ++mt) {                                      \
            int row = mt * 16 + l15;                                          \
            int byteoff = (cur) * 16384 + row * 256 +                         \
                          ((ks4 * 64 + l4 * 16) ^ ((row & 7) << 4));          \
            af[mt] = *(const bf16x8*)((const char*)A_lds + byteoff);          \
        }                                                                     \
        __builtin_amdgcn_s_setprio(1);                                        \
        _Pragma("unroll")                                                     \
        for (int mt = 0; mt < 4; ++mt)                                        \
            _Pragma("unroll")                                                 \
            for (int nt = 0; nt < 4; ++nt)                                    \
                acc[mt][nt] = __builtin_amdgcn_mfma_f32_16x16x32_bf16(        \
                    af[mt], bfb[nt], acc[mt][nt], 0, 0, 0);                   \
        __builtin_amdgcn_s_setprio(0);                                        \
    }

    // prologue: tile 0 staged to buf0
    LOADREGS(0);
    CONVWRITE(0);
    __syncthreads();

    int cur = 0;
#pragma unroll 1
    for (int kt = 0; kt < 7; ++kt) {
        LOADREGS(kt + 1);          // loads in flight across first compute half
        COMPUTE2(cur, kt, 0);
        CONVWRITE(cur ^ 1);        // mid-tile: vmcnt wait here, ds_writes drain below
        COMPUTE2(cur, kt, 2);
        __syncthreads();           // one barrier per K-tile
        cur ^= 1;
    }
    COMPUTE2(cur, 7, 0);           // tail tile
    COMPUTE2(cur, 7, 2);

#undef LOADREGS
#undef CONVWRITE
#undef COMPUTE2

    // epilogue: score[row] = sum_a tanh(y + x + b_g + b_s) * v[a], LDS-reduced
    float xbv[4], vv[4];
#pragma unroll
    for (int nt = 0; nt < 4; ++nt) {
        int a = wbase + nt * 16 + l15;
        xbv[nt] = xraw[bidx * 512 + a] + b_genes[a] + b_smiles[a];
        vv[nt]  = v[a];
    }
    float rs[4][4];
#pragma unroll
    for (int mt = 0; mt < 4; ++mt)
#pragma unroll
        for (int r = 0; r < 4; ++r)
            rs[mt][r] = 0.f;
#pragma unroll
    for (int mt = 0; mt < 4; ++mt)
#pragma unroll
        for (int nt = 0; nt < 4; ++nt)
#pragma unroll
            for (int r = 0; r < 4; ++r)
                rs[mt][r] += vv[nt] * fast_tanh(acc[mt][nt][r] + xbv[nt]);
#pragma unroll
    for (int mt = 0; mt < 4; ++mt)
#pragma unroll
        for (int r = 0; r < 4; ++r) {
            float s = rs[mt][r];
            s += __shfl_xor(s, 1);
            s += __shfl_xor(s, 2);
            s += __shfl_xor(s, 4);
            s += __shfl_xor(s, 8);
            rs[mt][r] = s;
        }
    if (l15 == 0) {
#pragma unroll
        for (int mt = 0; mt < 4; ++mt)
#pragma unroll
            for (int r = 0; r < 4; ++r)
                atomicAdd(&score_lds[mt * 16 + l4 * 4 + r], rs[mt][r]);
    }
    __syncthreads();
    if (tid < 64) scores[gm0 + tid] = score_lds[tid];
}

// K4: softmax (recomputed per block from scores, deterministic) + weighted sum.
// out[b][h] += sum_{t in chunk} alpha[b][t] * smiles[b][t][h]; t-split x32.
__global__ void k4_soft(const float* __restrict__ smiles,
                        const float* __restrict__ scores,
                        float* __restrict__ out)
{
    __shared__ float redmax[4], redsum[4], al_lds[64];
    int bx = blockIdx.x;              // 1024 = 32 b * 32 t-chunks
    int b  = bx >> 5;
    int tc = bx & 31;
    int tid = threadIdx.x;            // 256
    int wid = tid >> 6;

    // block-wide exact softmax stats over all 2048 scores of batch b
    float sv[8];
    float mx = -1e30f;
#pragma unroll
    for (int i = 0; i < 8; ++i) {
        sv[i] = scores[b * 2048 + i * 256 + tid];
        mx = fmaxf(mx, sv[i]);
    }
#pragma unroll
    for (int m = 32; m >= 1; m >>= 1) mx = fmaxf(mx, __shfl_xor(mx, m));
    if ((tid & 63) == 0) redmax[wid] = mx;
    __syncthreads();
    mx = fmaxf(fmaxf(redmax[0], redmax[1]), fmaxf(redmax[2], redmax[3]));
    float zp = 0.f;
#pragma unroll
    for (int i = 0; i < 8; ++i) zp += __expf(sv[i] - mx);
#pragma unroll
    for (int m = 32; m >= 1; m >>= 1) zp += __shfl_xor(zp, m);
    if ((tid & 63) == 0) redsum[wid] = zp;
    __syncthreads();
    float invZ = 1.f / (redsum[0] + redsum[1] + redsum[2] + redsum[3]);
    if (tid < 64)
        al_lds[tid] = __expf(scores[b * 2048 + tc * 64 + tid] - mx) * invZ;
    __syncthreads();

    int h = tid * 4;                  // 256 threads -> 1024 h
    const float* sb = smiles + ((size_t)b * 2048 + tc * 64) * 1024;
    float4 acc = {0.f, 0.f, 0.f, 0.f};
#pragma unroll 4
    for (int t = 0; t < 64; ++t) {
        float a = al_lds[t];
        float4 sv4 = *(const float4*)(sb + (size_t)t * 1024 + h);
        acc.x += a * sv4.x;
        acc.y += a * sv4.y;
        acc.z += a * sv4.z;
        acc.w += a * sv4.w;
    }
    float* o = out + b * 1024 + h;
    atomicAdd(o + 0, acc.x);
    atomicAdd(o + 1, acc.y);
    atomicAdd(o + 2, acc.z);
    atomicAdd(o + 3, acc.w);
}

extern "C" void kernel_launch(void* const* d_in, const int* in_sizes, int n_in,
                              void* d_out, int out_size, void* d_ws, size_t ws_size,
                              hipStream_t stream) {
    const float* genes    = (const float*)d_in[0];
    const float* smiles   = (const float*)d_in[1];
    const float* w_ngf    = (const float*)d_in[2];
    const float* w_genes  = (const float*)d_in[3];
    const float* b_genes  = (const float*)d_in[4];
    const float* w_smiles = (const float*)d_in[5];
    const float* b_smiles = (const float*)d_in[6];
    const float* v        = (const float*)d_in[7];
    float* out = (float*)d_out;

    char* ws = (char*)d_ws;
    unsigned short* Bp = (unsigned short*)(ws);                        // 1 MB packed B
    float* gc     = (float*)(ws + (1 << 20));                          // 256 KB
    float* x      = (float*)(ws + (1 << 20) + (256 << 10));            // 64 KB
    float* scores = (float*)(ws + (1 << 20) + (320 << 10));            // 256 KB

    hipMemsetAsync(out, 0, (size_t)32 * 1024 * sizeof(float), stream);
    hipMemsetAsync(x, 0, (size_t)64 * 1024, stream);

    k0b_pack<<<1024, 64, 0, stream>>>(w_smiles, Bp);
    k1a_gc<<<256, 256, 0, stream>>>((const float4*)genes, w_ngf, gc);
    k1b_x<<<512, 256, 0, stream>>>(gc, w_genes, x);
    k2_scores<<<1024, 512, 0, stream>>>(smiles, Bp, x, b_genes, b_smiles, v, scores);
    k4_soft<<<1024, 256, 0, stream>>>(smiles, scores, out);
}

// Round 9
// 163.847 us; speedup vs baseline: 1.1531x; 1.0514x over previous
//
#include <hip/hip_runtime.h>

// Shapes: genes[32][2048][4], smiles[32][2048][1024], w_ngf[4], w_genes[2048][512],
//         b_genes[512], w_smiles[1024][512], b_smiles[512], v[512] -> out[32][1024]

typedef __bf16 bf16_t;
typedef bf16_t bf16x8 __attribute__((ext_vector_type(8)));
typedef float f32x4 __attribute__((ext_vector_type(4)));

__device__ __forceinline__ unsigned short f32_to_bf16_rne(float f) {
    unsigned int u = __builtin_bit_cast(unsigned int, f);
    u = (u + 0x7FFFu + ((u >> 16) & 1u)) >> 16;
    return (unsigned short)u;
}

__device__ __forceinline__ float fast_tanh(float x) {
    float cx = fminf(fmaxf(x, -30.f), 30.f);
    float e = __expf(2.f * cx);
    return (e - 1.f) / (e + 1.f);
}

// K0b: pack w_smiles [1024][512] f32 into FRAGMENT-MAJOR bf16 (16x16 frags).
// Bp[frag=atile*32+gks][lane][e] = w[gks*32 + (lane>>4)*8 + e][atile*16 + (lane&15)]
__global__ void k0b_pack(const float* __restrict__ w, unsigned short* __restrict__ Bp) {
    int bid  = blockIdx.x;        // 1024 = 32 atiles * 32 gks
    int lane = threadIdx.x;       // 64
    int atile = bid >> 5, gks = bid & 31;
    int col = atile * 16 + (lane & 15);
    int k0  = gks * 32 + (lane >> 4) * 8;
    unsigned short us[8];
#pragma unroll
    for (int e = 0; e < 8; ++e)
        us[e] = f32_to_bf16_rne(w[(size_t)(k0 + e) * 512 + col]);
    *(uint4*)(Bp + (size_t)bid * 512 + lane * 8) = *(const uint4*)us;
}

// K1a: gc[b][g] = dot(genes[b][g][0..3], w_ngf)
__global__ void k1a_gc(const float4* __restrict__ genes, const float* __restrict__ wngf,
                       float* __restrict__ gc) {
    int i = blockIdx.x * 256 + threadIdx.x;   // 65536 = 32*2048
    float4 g = genes[i];
    gc[i] = g.x * wngf[0] + g.y * wngf[1] + g.z * wngf[2] + g.w * wngf[3];
}

// K1b: x[b][a] += sum_{g in chunk} gc[b][g] * w_genes[g][a]   (x pre-zeroed)
__global__ void k1b_x(const float* __restrict__ gc, const float* __restrict__ wg,
                      float* __restrict__ x) {
    __shared__ float gcl[256];
    int bx = blockIdx.x;              // 512 = 32 b * 2 a-halves * 8 g-chunks
    int b = bx >> 4, ah = (bx >> 3) & 1, gch = bx & 7;
    int g0 = gch * 256;
    gcl[threadIdx.x] = gc[b * 2048 + g0 + threadIdx.x];
    __syncthreads();
    int a = ah * 256 + threadIdx.x;
    float s = 0.f;
#pragma unroll 8
    for (int g = 0; g < 256; ++g) s += gcl[g] * wg[(size_t)(g0 + g) * 512 + a];
    atomicAdd(&x[b * 512 + a], s);
}

// K2: fused GEMM + tanh + dot(v) -> scores.  EXACT R3 K-loop schedule:
//   LOADREGS(kt+1) -> COMPUTE(kt) all 4 ks -> CONVWRITE -> one __syncthreads.
// (R8's mid-tile CONVWRITE regressed ~10us: st-regs live across a compute half
//  at the 64-VGPR wall. Reverted.)
// Epilogue: per-wave partial scores reduced via LDS atomics, single store.
__global__ __launch_bounds__(512, 4) void k2_scores(
    const float* __restrict__ smiles,
    const unsigned short* __restrict__ Bp,
    const float* __restrict__ xraw,
    const float* __restrict__ b_genes,
    const float* __restrict__ b_smiles,
    const float* __restrict__ v,
    float* __restrict__ scores)
{
    __shared__ unsigned short A_lds[2 * 64 * 128];   // 32 KB, XOR-swizzled 256B rows
    __shared__ float score_lds[64];
    const int tid  = threadIdx.x;
    const int wave = tid >> 6;
    const int lane = tid & 63;
    const int l15  = lane & 15;
    const int l4   = lane >> 4;
    const int gm0  = blockIdx.x * 64;            // 1024 blocks
    const int bidx = gm0 >> 11;
    const int wbase = wave * 64;

    // wave's packed-B base: fragments (wave*4+nt)*32 + gks, each 1KB
    const unsigned short* bpp = Bp + (size_t)(wave * 128) * 512 + lane * 8;

    // staging geometry: thread owns 16 consecutive floats of the 64x128 tile
    const int srow = tid >> 3;                   // 0..63
    const float* sptr = smiles + (size_t)(gm0 + srow) * 1024 + (tid & 7) * 16;
    const int sswz = (srow & 7) << 4;
    char* wr0 = (char*)A_lds + srow * 256 + (((tid & 7) * 32) ^ sswz);
    char* wr1 = (char*)A_lds + srow * 256 + ((((tid & 7) * 32) + 16) ^ sswz);

    if (tid < 64) score_lds[tid] = 0.f;

    float4 st0, st1, st2, st3;

    const f32x4 zero4 = {0.f, 0.f, 0.f, 0.f};
    f32x4 acc[4][4];
#pragma unroll
    for (int mt = 0; mt < 4; ++mt)
#pragma unroll
        for (int nt = 0; nt < 4; ++nt)
            acc[mt][nt] = zero4;

#define LOADREGS(kt)                                   \
    {   const float* p = sptr + (kt) * 128;            \
        st0 = *(const float4*)(p);                     \
        st1 = *(const float4*)(p + 4);                 \
        st2 = *(const float4*)(p + 8);                 \
        st3 = *(const float4*)(p + 12); }

#define CONVWRITE(buf)                                                     \
    {   union { unsigned short us[8]; uint4 u4; } pa, pb;                  \
        pa.us[0] = f32_to_bf16_rne(st0.x); pa.us[1] = f32_to_bf16_rne(st0.y); \
        pa.us[2] = f32_to_bf16_rne(st0.z); pa.us[3] = f32_to_bf16_rne(st0.w); \
        pa.us[4] = f32_to_bf16_rne(st1.x); pa.us[5] = f32_to_bf16_rne(st1.y); \
        pa.us[6] = f32_to_bf16_rne(st1.z); pa.us[7] = f32_to_bf16_rne(st1.w); \
        pb.us[0] = f32_to_bf16_rne(st2.x); pb.us[1] = f32_to_bf16_rne(st2.y); \
        pb.us[2] = f32_to_bf16_rne(st2.z); pb.us[3] = f32_to_bf16_rne(st2.w); \
        pb.us[4] = f32_to_bf16_rne(st3.x); pb.us[5] = f32_to_bf16_rne(st3.y); \
        pb.us[6] = f32_to_bf16_rne(st3.z); pb.us[7] = f32_to_bf16_rne(st3.w); \
        *(uint4*)(wr0 + (buf) * 16384) = pa.u4;                            \
        *(uint4*)(wr1 + (buf) * 16384) = pb.u4; }

#define COMPUTE(cur, kt)                                                      \
    _Pragma("unroll")                                                         \
    for (int ks4 = 0; ks4 < 4; ++ks4) {                                       \
        int gks = (kt) * 4 + ks4;                                             \
        bf16x8 af[4], bfb[4];                                                 \
        _Pragma("unroll")                                                     \
        for (int nt = 0; nt < 4; ++nt)                                        \
            bfb[nt] = *(const bf16x8*)(bpp + (nt * 32 + gks) * 512);          \
        _Pragma("unroll")                                                     \
        for (int mt = 0; mt < 4; ++mt) {                                      \
            int row = mt * 16 + l15;                                          \
            int byteoff = (cur) * 16384 + row * 256 +                         \
                          ((ks4 * 64 + l4 * 16) ^ ((row & 7) << 4));          \
            af[mt] = *(const bf16x8*)((const char*)A_lds + byteoff);          \
        }                                                                     \
        __builtin_amdgcn_s_setprio(1);                                        \
        _Pragma("unroll")                                                     \
        for (int mt = 0; mt < 4; ++mt)                                        \
            _Pragma("unroll")                                                 \
            for (int nt = 0; nt < 4; ++nt)                                    \
                acc[mt][nt] = __builtin_amdgcn_mfma_f32_16x16x32_bf16(        \
                    af[mt], bfb[nt], acc[mt][nt], 0, 0, 0);                   \
        __builtin_amdgcn_s_setprio(0);                                        \
    }

    // prologue: tile 0 staged to buf0
    LOADREGS(0);
    CONVWRITE(0);
    __syncthreads();

    int cur = 0;
#pragma unroll 1
    for (int kt = 0; kt < 7; ++kt) {
        LOADREGS(kt + 1);          // issue early; MFMAs below hide the HBM latency
        COMPUTE(cur, kt);
        CONVWRITE(cur ^ 1);        // compiler-counted vmcnt wait lands here
        __syncthreads();           // one barrier per K-tile
        cur ^= 1;
    }
    COMPUTE(cur, 7);               // tail tile

#undef LOADREGS
#undef CONVWRITE
#undef COMPUTE

    // epilogue: score[row] = sum_a tanh(y + x + b_g + b_s) * v[a], LDS-reduced
    float xbv[4], vv[4];
#pragma unroll
    for (int nt = 0; nt < 4; ++nt) {
        int a = wbase + nt * 16 + l15;
        xbv[nt] = xraw[bidx * 512 + a] + b_genes[a] + b_smiles[a];
        vv[nt]  = v[a];
    }
    float rs[4][4];
#pragma unroll
    for (int mt = 0; mt < 4; ++mt)
#pragma unroll
        for (int r = 0; r < 4; ++r)
            rs[mt][r] = 0.f;
#pragma unroll
    for (int mt = 0; mt < 4; ++mt)
#pragma unroll
        for (int nt = 0; nt < 4; ++nt)
#pragma unroll
            for (int r = 0; r < 4; ++r)
                rs[mt][r] += vv[nt] * fast_tanh(acc[mt][nt][r] + xbv[nt]);
#pragma unroll
    for (int mt = 0; mt < 4; ++mt)
#pragma unroll
        for (int r = 0; r < 4; ++r) {
            float s = rs[mt][r];
            s += __shfl_xor(s, 1);
            s += __shfl_xor(s, 2);
            s += __shfl_xor(s, 4);
            s += __shfl_xor(s, 8);
            rs[mt][r] = s;
        }
    if (l15 == 0) {
#pragma unroll
        for (int mt = 0; mt < 4; ++mt)
#pragma unroll
            for (int r = 0; r < 4; ++r)
                atomicAdd(&score_lds[mt * 16 + l4 * 4 + r], rs[mt][r]);
    }
    __syncthreads();
    if (tid < 64) scores[gm0 + tid] = score_lds[tid];
}

// K4: softmax (recomputed per block from scores, deterministic) + weighted sum.
// out[b][h] += sum_{t in chunk} alpha[b][t] * smiles[b][t][h]; t-split x32.
__global__ void k4_soft(const float* __restrict__ smiles,
                        const float* __restrict__ scores,
                        float* __restrict__ out)
{
    __shared__ float redmax[4], redsum[4], al_lds[64];
    int bx = blockIdx.x;              // 1024 = 32 b * 32 t-chunks
    int b  = bx >> 5;
    int tc = bx & 31;
    int tid = threadIdx.x;            // 256
    int wid = tid >> 6;

    // block-wide exact softmax stats over all 2048 scores of batch b
    float sv[8];
    float mx = -1e30f;
#pragma unroll
    for (int i = 0; i < 8; ++i) {
        sv[i] = scores[b * 2048 + i * 256 + tid];
        mx = fmaxf(mx, sv[i]);
    }
#pragma unroll
    for (int m = 32; m >= 1; m >>= 1) mx = fmaxf(mx, __shfl_xor(mx, m));
    if ((tid & 63) == 0) redmax[wid] = mx;
    __syncthreads();
    mx = fmaxf(fmaxf(redmax[0], redmax[1]), fmaxf(redmax[2], redmax[3]));
    float zp = 0.f;
#pragma unroll
    for (int i = 0; i < 8; ++i) zp += __expf(sv[i] - mx);
#pragma unroll
    for (int m = 32; m >= 1; m >>= 1) zp += __shfl_xor(zp, m);
    if ((tid & 63) == 0) redsum[wid] = zp;
    __syncthreads();
    float invZ = 1.f / (redsum[0] + redsum[1] + redsum[2] + redsum[3]);
    if (tid < 64)
        al_lds[tid] = __expf(scores[b * 2048 + tc * 64 + tid] - mx) * invZ;
    __syncthreads();

    int h = tid * 4;                  // 256 threads -> 1024 h
    const float* sb = smiles + ((size_t)b * 2048 + tc * 64) * 1024;
    float4 acc = {0.f, 0.f, 0.f, 0.f};
#pragma unroll 4
    for (int t = 0; t < 64; ++t) {
        float a = al_lds[t];
        float4 sv4 = *(const float4*)(sb + (size_t)t * 1024 + h);
        acc.x += a * sv4.x;
        acc.y += a * sv4.y;
        acc.z += a * sv4.z;
        acc.w += a * sv4.w;
    }
    float* o = out + b * 1024 + h;
    atomicAdd(o + 0, acc.x);
    atomicAdd(o + 1, acc.y);
    atomicAdd(o + 2, acc.z);
    atomicAdd(o + 3, acc.w);
}

extern "C" void kernel_launch(void* const* d_in, const int* in_sizes, int n_in,
                              void* d_out, int out_size, void* d_ws, size_t ws_size,
                              hipStream_t stream) {
    const float* genes    = (const float*)d_in[0];
    const float* smiles   = (const float*)d_in[1];
    const float* w_ngf    = (const float*)d_in[2];
    const float* w_genes  = (const float*)d_in[3];
    const float* b_genes  = (const float*)d_in[4];
    const float* w_smiles = (const float*)d_in[5];
    const float* b_smiles = (const float*)d_in[6];
    const float* v        = (const float*)d_in[7];
    float* out = (float*)d_out;

    char* ws = (char*)d_ws;
    unsigned short* Bp = (unsigned short*)(ws);                        // 1 MB packed B
    float* gc     = (float*)(ws + (1 << 20));                          // 256 KB
    float* x      = (float*)(ws + (1 << 20) + (256 << 10));            // 64 KB
    float* scores = (float*)(ws + (1 << 20) + (320 << 10));            // 256 KB

    hipMemsetAsync(out, 0, (size_t)32 * 1024 * sizeof(float), stream);
    hipMemsetAsync(x, 0, (size_t)64 * 1024, stream);

    k0b_pack<<<1024, 64, 0, stream>>>(w_smiles, Bp);
    k1a_gc<<<256, 256, 0, stream>>>((const float4*)genes, w_ngf, gc);
    k1b_x<<<512, 256, 0, stream>>>(gc, w_genes, x);
    k2_scores<<<1024, 512, 0, stream>>>(smiles, Bp, x, b_genes, b_smiles, v, scores);
    k4_soft<<<1024, 256, 0, stream>>>(smiles, scores, out);
}